// Round 8
// baseline (450.124 us; speedup 1.0000x reference)
//
#include <hip/hip_runtime.h>
#include <stdint.h>

#define NN 50000
#define EE 800000
#define INF_ 256
#define OUTF 32
#define HH 8
#define NEG_SLOPE 0.2f
#define EPS_ 1e-8f
#define SCAN_B 196   // ceil(NN/256)

typedef unsigned short u16;
typedef unsigned int u32;
typedef short short8 __attribute__((ext_vector_type(8)));
typedef float f32x4 __attribute__((ext_vector_type(4)));

__device__ __forceinline__ float bflo(u32 w){ return __uint_as_float(w << 16); }
__device__ __forceinline__ float bfhi(u32 w){ return __uint_as_float(w & 0xFFFF0000u); }
__device__ __forceinline__ u16 f2bf(float f){
  u32 u = __float_as_uint(f);
  u += 0x7FFFu + ((u >> 16) & 1u);   // round-to-nearest-even
  return (u16)(u >> 16);
}

// ---------------- p-vectors (fp32): p[h,i] = sum_f W[h,i,f] * a[h,f] ----------------
__global__ void k_pvec(const float* __restrict__ W, const float* __restrict__ a_src,
                       const float* __restrict__ a_dst, float* __restrict__ p_src,
                       float* __restrict__ p_dst){
  int idx = blockIdx.x*blockDim.x + threadIdx.x;   // h*256 + i
  if (idx >= HH*INF_) return;
  int h = idx >> 8;
  const float* w = W + idx*OUTF;
  float ps = 0.f, pd = 0.f;
#pragma unroll
  for (int f = 0; f < OUTF; ++f){
    float wv = w[f];
    ps += wv * a_src[h*OUTF + f];
    pd += wv * a_dst[h*OUTF + f];
  }
  p_src[idx] = ps; p_dst[idx] = pd;
}

// ------- fused: x fp32 -> x_bf (bf16) + fp32 scores s_src/s_dst via p-vectors -------
// one wave per node (4 nodes per wave via loop); lane l owns x[n][4l..4l+3]
__global__ __launch_bounds__(256) void k_score_cvt(const float* __restrict__ x,
    const float* __restrict__ p_src, const float* __restrict__ p_dst,
    u16* __restrict__ xb, float* __restrict__ s_src, float* __restrict__ s_dst){
  __shared__ float pl[16*INF_];   // 16 KB: pair = h*2 + t (t: 0=src,1=dst)
  int tid = threadIdx.x;
#pragma unroll
  for (int k = 0; k < 4; ++k){
    int idx4 = tid + k*256;            // 1024 float4s total
    int pair = idx4 >> 6, i4 = idx4 & 63;
    const float* src = ((pair & 1) ? p_dst : p_src) + (pair >> 1)*INF_;
    *(float4*)&pl[pair*INF_ + i4*4] = ((const float4*)src)[i4];
  }
  __syncthreads();
  int wv = tid >> 6, lane = tid & 63;
#pragma unroll
  for (int nl = 0; nl < 4; ++nl){
    int n = blockIdx.x*16 + wv*4 + nl;          // 3125*16 = 50000 exactly
    float4 xv = ((const float4*)(x + (size_t)n*INF_))[lane];
    ushort4 o; o.x = f2bf(xv.x); o.y = f2bf(xv.y); o.z = f2bf(xv.z); o.w = f2bf(xv.w);
    *(ushort4*)(xb + (size_t)n*INF_ + lane*4) = o;
    float v[16];
#pragma unroll
    for (int pr = 0; pr < 16; ++pr){
      float4 pv = *(const float4*)&pl[pr*INF_ + lane*4];
      v[pr] = xv.x*pv.x + xv.y*pv.y + xv.z*pv.z + xv.w*pv.w;
    }
#pragma unroll
    for (int m = 1; m < 64; m <<= 1)
#pragma unroll
      for (int j = 0; j < 16; ++j)
        v[j] += __shfl_xor(v[j], m, 64);
    if (lane < 16){
      float sel = v[0];
#pragma unroll
      for (int j = 1; j < 16; ++j) sel = (lane == j) ? v[j] : sel;
      float* dstp = (lane & 1) ? s_dst : s_src;
      dstp[n*8 + (lane >> 1)] = sel;
    }
  }
}

// ---------------- prep: W fp32 [H][K][F] -> Wt bf16 [c=h*32+f][k] ----------------
__global__ __launch_bounds__(256) void k_prep_w(const float* __restrict__ W,
                                                u16* __restrict__ wt){
  int idx = blockIdx.x*256 + threadIdx.x;       // c*64 + k4 ; 16384 total
  int c = idx >> 6, k4 = idx & 63;
  int h = c >> 5, f = c & 31;
  const float* wp = W + h*(INF_*OUTF) + f;
  ushort4 o;
  o.x = f2bf(wp[(k4*4+0)*OUTF]);
  o.y = f2bf(wp[(k4*4+1)*OUTF]);
  o.z = f2bf(wp[(k4*4+2)*OUTF]);
  o.w = f2bf(wp[(k4*4+3)*OUTF]);
  ((ushort4*)wt)[idx] = o;                      // wt[c*256 + k4*4 .. +3]
}

// ---------------- MFMA GEMM: h_bf[n, c] = bf16( sum_k x[n,k] Wt[c,k] ) ----------------
#define BM 128
#define BN 128
#define BK 64
#define ASTR 72   // LDS row stride in shorts (144 B, 16B-aligned, non-pow2)

__global__ __launch_bounds__(256) void k_gemm(const u16* __restrict__ xb,
                                              const u16* __restrict__ wt,
                                              u16* __restrict__ h_out){
  __shared__ u16 Al[BM*ASTR];
  __shared__ u16 Bl[BN*ASTR];
  int tid = threadIdx.x;
  int bx = blockIdx.x & 1;          // col half: heads 0-3 / 4-7
  int by = blockIdx.x >> 1;
  int n0 = by*BM, c0 = bx*BN;
  int w = tid >> 6, l = tid & 63;
  int g = l >> 4, i = l & 15;       // quad, lane-in-quad16
  int rowbase = (w >> 1) * 64, colbase = (w & 1) * 64;

  f32x4 acc[4][4];
#pragma unroll
  for (int rt = 0; rt < 4; ++rt)
#pragma unroll
    for (int ct = 0; ct < 4; ++ct)
      acc[rt][ct] = (f32x4){0.f, 0.f, 0.f, 0.f};

  int st_row = tid >> 1, st_half = tid & 1;     // stage 64 B per thread

  for (int kb = 0; kb < 4; ++kb){
    {
      int n = n0 + st_row;
      uint4 z = make_uint4(0u,0u,0u,0u);
      uint4 u0=z, u1=z, u2=z, u3=z;
      if (n < NN){
        const uint4* src = (const uint4*)(xb + (size_t)n*INF_ + kb*64 + st_half*32);
        u0 = src[0]; u1 = src[1]; u2 = src[2]; u3 = src[3];
      }
      u16* dst = &Al[st_row*ASTR + st_half*32];
      *(uint4*)(dst +  0) = u0;
      *(uint4*)(dst +  8) = u1;
      *(uint4*)(dst + 16) = u2;
      *(uint4*)(dst + 24) = u3;
    }
    {
      const uint4* src = (const uint4*)(wt + (size_t)(c0 + st_row)*INF_ + kb*64 + st_half*32);
      uint4 u0 = src[0], u1 = src[1], u2 = src[2], u3 = src[3];
      u16* dst = &Bl[st_row*ASTR + st_half*32];
      *(uint4*)(dst +  0) = u0;
      *(uint4*)(dst +  8) = u1;
      *(uint4*)(dst + 16) = u2;
      *(uint4*)(dst + 24) = u3;
    }
    __syncthreads();
#pragma unroll
    for (int ks = 0; ks < 2; ++ks){
      short8 af[4], bf[4];
#pragma unroll
      for (int rt = 0; rt < 4; ++rt)
        af[rt] = *(const short8*)&Al[(rowbase + rt*16 + i)*ASTR + ks*32 + g*8];
#pragma unroll
      for (int ct = 0; ct < 4; ++ct)
        bf[ct] = *(const short8*)&Bl[(colbase + ct*16 + i)*ASTR + ks*32 + g*8];
#pragma unroll
      for (int rt = 0; rt < 4; ++rt)
#pragma unroll
        for (int ct = 0; ct < 4; ++ct)
          acc[rt][ct] = __builtin_amdgcn_mfma_f32_16x16x32_bf16(af[rt], bf[ct], acc[rt][ct], 0, 0, 0);
    }
    __syncthreads();
  }

  // ---- h output: D[m][n]: m(node) = quad*4+reg, n(col) = lane&15 ----
#pragma unroll
  for (int rt = 0; rt < 4; ++rt)
#pragma unroll
    for (int e = 0; e < 4; ++e){
      int n = n0 + rowbase + rt*16 + g*4 + e;
      if (n < NN){
        u16* hp = h_out + (size_t)n*INF_ + c0 + colbase;
        hp[ 0 + i] = f2bf(acc[rt][0][e]);
        hp[16 + i] = f2bf(acc[rt][1][e]);
        hp[32 + i] = f2bf(acc[rt][2][e]);
        hp[48 + i] = f2bf(acc[rt][3][e]);
      }
    }
}

// ---------------- CSR build: hist -> hierarchical scan -> scatter -> canonical sort ----------------
__global__ void k_hist(const int* __restrict__ ei, int* __restrict__ count){
  int e = blockIdx.x*blockDim.x + threadIdx.x;
  if (e < EE) atomicAdd(&count[ei[EE + e]], 1);
}

__global__ void k_scan1(const int* __restrict__ count, int* __restrict__ bsum){
  __shared__ int lds[4];
  int t = threadIdx.x;
  int idx = blockIdx.x*256 + t;
  int v = (idx < NN) ? count[idx] : 0;
#pragma unroll
  for (int off = 32; off > 0; off >>= 1) v += __shfl_down(v, off, 64);
  if ((t & 63) == 0) lds[t >> 6] = v;
  __syncthreads();
  if (t == 0) bsum[blockIdx.x] = lds[0] + lds[1] + lds[2] + lds[3];
}

__global__ void k_scan2(const int* __restrict__ bsum, int* __restrict__ boff){
  __shared__ int lds[256];
  int t = threadIdx.x;
  int v = (t < SCAN_B) ? bsum[t] : 0;
  lds[t] = v;
  __syncthreads();
  for (int off = 1; off < 256; off <<= 1){
    int add = (t >= off) ? lds[t - off] : 0;
    __syncthreads();
    lds[t] += add;
    __syncthreads();
  }
  if (t < SCAN_B) boff[t] = lds[t] - v;   // exclusive prefix of block sums
}

__global__ void k_scan3(const int* __restrict__ count, const int* __restrict__ boff,
                        int* __restrict__ row_ptr, int* __restrict__ w_off){
  __shared__ int lds[256];
  int t = threadIdx.x;
  int idx = blockIdx.x*256 + t;
  int v = (idx < NN) ? count[idx] : 0;
  lds[t] = v;
  __syncthreads();
  for (int off = 1; off < 256; off <<= 1){
    int add = (t >= off) ? lds[t - off] : 0;
    __syncthreads();
    lds[t] += add;
    __syncthreads();
  }
  int excl = boff[blockIdx.x] + lds[t] - v;
  if (idx < NN){ row_ptr[idx] = excl; w_off[idx] = excl; }
  if (idx == 0) row_ptr[NN] = EE;
}

__global__ void k_scatter(const int* __restrict__ ei, int* __restrict__ w_off,
                          int* __restrict__ csr){
  int e = blockIdx.x*blockDim.x + threadIdx.x;
  if (e < EE){
    int d = ei[EE + e];
    int pos = atomicAdd(&w_off[d], 1);
    csr[pos] = ei[e];              // src node id
  }
}

// Canonicalize each CSR row (ascending src) -> deterministic downstream accumulation.
__global__ void k_sort(const int* __restrict__ row_ptr, int* __restrict__ csr){
  int n = blockIdx.x*256 + threadIdx.x;
  if (n >= NN) return;
  int beg = row_ptr[n], end = row_ptr[n+1];
  for (int i = beg + 1; i < end; ++i){
    int v = csr[i];
    int j = i - 1;
    while (j >= beg && csr[j] > v){ csr[j+1] = csr[j]; --j; }
    csr[j+1] = v;
  }
}

// ---------------- fused online-softmax aggregation: one wave per dst node ----------------
__global__ __launch_bounds__(256) void k_agg(const int* __restrict__ row_ptr,
    const int* __restrict__ csr, const float* __restrict__ s_src,
    const float* __restrict__ s_dst, const u16* __restrict__ h_bf,
    float* __restrict__ out){
  int lane = threadIdx.x & 63;
  int n = blockIdx.x*4 + (threadIdx.x >> 6);
  if (n >= NN) return;
  int h = lane >> 3, q = lane & 7;          // lane owns head h, f in [q*4, q*4+4)
  float sd = s_dst[n*8 + h];
  int beg = row_ptr[n], end = row_ptr[n+1];
  float m = -1e30f, l = 0.f;
  float a0=0.f, a1=0.f, a2=0.f, a3=0.f;
  for (int j = beg; j < end; ++j){
    int src = csr[j];
    float sc = s_src[src*8 + h] + sd;
    sc = sc > 0.f ? sc : NEG_SLOPE*sc;      // LeakyReLU
    float mn = fmaxf(m, sc);
    float scale = __expf(m - mn);           // exp(-huge)=0 handles first edge
    float p = __expf(sc - mn);
    m = mn;
    l = l*scale + p;
    uint2 hv = *(const uint2*)(h_bf + (size_t)src*INF_ + h*32 + q*4);
    a0 = a0*scale + p*bflo(hv.x);
    a1 = a1*scale + p*bfhi(hv.x);
    a2 = a2*scale + p*bflo(hv.y);
    a3 = a3*scale + p*bfhi(hv.y);
  }
  float inv = 1.f/(l + EPS_);
  float4 o = make_float4(a0*inv, a1*inv, a2*inv, a3*inv);
  *(float4*)(out + (size_t)n*INF_ + h*32 + q*4) = o;
}

// ---------------- launch ----------------
extern "C" void kernel_launch(void* const* d_in, const int* in_sizes, int n_in,
                              void* d_out, int out_size, void* d_ws, size_t ws_size,
                              hipStream_t stream){
  const float* x     = (const float*)d_in[0];
  const int*   ei    = (const int*)d_in[1];
  const float* W     = (const float*)d_in[2];
  const float* a_src = (const float*)d_in[3];
  const float* a_dst = (const float*)d_in[4];
  float* out = (float*)d_out;
  char* ws = (char*)d_ws;

  u16*   x_bf    = (u16*)  (ws + 0);          // 25,600,000 B
  u16*   h_bf    = (u16*)  (ws + 25600000);   // 25,600,000 B
  float* s_src   = (float*)(ws + 51200000);   //  1,600,000 B
  float* s_dst   = (float*)(ws + 52800000);   //  1,600,000 B
  int*   count   = (int*)  (ws + 54400000);   //    200,000 B
  int*   row_ptr = (int*)  (ws + 54600000);   //    200,004 B
  int*   w_off   = (int*)  (ws + 54800064);   //    200,000 B
  int*   csr     = (int*)  (ws + 55000064);   //  3,200,000 B
  int*   bsum    = (int*)  (ws + 58200064);   //        784 B
  int*   boff    = (int*)  (ws + 58200864);   //        784 B
  u16*   wt      = (u16*)  (ws + 58201664);   //    131,072 B
  float* p_src   = (float*)(ws + 58332736);   //      8,192 B
  float* p_dst   = (float*)(ws + 58340928);   //      8,192 B

  hipMemsetAsync(count, 0, NN*sizeof(int), stream);
  k_pvec<<<8, 256, 0, stream>>>(W, a_src, a_dst, p_src, p_dst);
  k_prep_w<<<64, 256, 0, stream>>>(W, wt);
  k_score_cvt<<<3125, 256, 0, stream>>>(x, p_src, p_dst, x_bf, s_src, s_dst);
  k_gemm<<<((NN + BM - 1)/BM) * 2, 256, 0, stream>>>(x_bf, wt, h_bf);
  k_hist<<<EE/256, 256, 0, stream>>>(ei, count);
  k_scan1<<<SCAN_B, 256, 0, stream>>>(count, bsum);
  k_scan2<<<1, 256, 0, stream>>>(bsum, boff);
  k_scan3<<<SCAN_B, 256, 0, stream>>>(count, boff, row_ptr, w_off);
  k_scatter<<<EE/256, 256, 0, stream>>>(ei, w_off, csr);
  k_sort<<<SCAN_B, 256, 0, stream>>>(row_ptr, csr);
  k_agg<<<(NN + 3)/4, 256, 0, stream>>>(row_ptr, csr, s_src, s_dst, h_bf, out);
}